// Round 2
// baseline (15396.666 us; speedup 1.0000x reference)
//
#include <hip/hip_runtime.h>
#include <hip/hip_bf16.h>
#include <hip/hip_cooperative_groups.h>

namespace cg = cooperative_groups;

// Problem constants
#define HID    1024
#define ZS     128
#define NCOND  40
#define CSIZE  100
#define INSZ   228      // ZS + CSIZE
#define XSZ    1252     // HID + INSZ
#define NVOCAB 32000
#define NSTEPS 512

typedef __attribute__((ext_vector_type(8))) short bf16x8;
typedef __attribute__((ext_vector_type(4))) float f32x4;

__device__ __forceinline__ float wave_sum(float v) {
#pragma unroll
    for (int off = 32; off > 0; off >>= 1) v += __shfl_xor(v, off);
    return v;
}

// ---------------------------------------------------------------------------
// K1: de = [z, c2h(cond)] (fp32), h0 = i2h(de) -> hbuf[0:1024].
// grid 4 x 256: every block computes de in LDS; block b does h0 rows b*256+t.
// ---------------------------------------------------------------------------
__global__ void k_setup(const float* __restrict__ z,
                        const float* __restrict__ cond,
                        const float* __restrict__ i2hW,
                        const float* __restrict__ i2hb,
                        const float* __restrict__ c2hW,
                        const float* __restrict__ c2hb,
                        float* __restrict__ de, float* __restrict__ h0) {
    __shared__ float de_s[INSZ];
    const int t = threadIdx.x;
    if (t < ZS) {
        de_s[t] = z[t];
    } else if (t < INSZ) {
        const int i = t - ZS;
        float acc = c2hb[i];
        for (int k = 0; k < NCOND; k++)
            acc += c2hW[i * NCOND + k] * cond[k];
        de_s[t] = acc;
    }
    __syncthreads();
    if (blockIdx.x == 0 && t < INSZ) de[t] = de_s[t];
    const int r = blockIdx.x * 256 + t;   // 0..1023
    float acc = i2hb[r];
    const float* w = i2hW + (size_t)r * INSZ;   // 912B row stride, 16B aligned
#pragma unroll 8
    for (int k = 0; k < INSZ; k += 4) {
        const float4 wv = *(const float4*)(w + k);
        const float4 xv = *(const float4*)(de_s + k);
        acc += wv.x * xv.x + wv.y * xv.y + wv.z * xv.z + wv.w * xv.w;
    }
    h0[r] = acc;
}

// ---------------------------------------------------------------------------
// K2: gi[vec][3072] = W_ih @ [relu(embed[tok]), de] + b_ih, vec 0=SOS 1=UNK.
// grid 96 x 256: vec = bid&1, rows (bid>>1)*64 .. +64.
// ---------------------------------------------------------------------------
__global__ void k_gi(const float* __restrict__ embedW,
                     const float* __restrict__ W_ih,
                     const float* __restrict__ b_ih,
                     const float* __restrict__ de,
                     float* __restrict__ gi) {
    __shared__ float x_s[XSZ];
    const int g = blockIdx.x, t = threadIdx.x;
    const int vec = g & 1, rb = g >> 1;
    const int tok = 1 + vec;  // SOS=1, UNK=2
    for (int i = t; i < HID; i += 256) {
        float e = embedW[(size_t)tok * HID + i];
        x_s[i] = e > 0.f ? e : 0.f;
    }
    for (int i = t; i < INSZ; i += 256) x_s[HID + i] = de[i];
    __syncthreads();
    const int w = t >> 6, lane = t & 63;
    for (int rr = 0; rr < 16; rr++) {
        const int row = rb * 64 + w * 16 + rr;
        const float* wr = W_ih + (size_t)row * XSZ;  // 5008B stride, 16B aligned
        float acc = 0.f;
#pragma unroll
        for (int cc = 0; cc < 5; cc++) {
            const int k = cc * 256 + lane * 4;
            if (k < XSZ) {
                const float4 wv = *(const float4*)(wr + k);
                const float4 xv = *(const float4*)(x_s + k);
                acc += wv.x * xv.x + wv.y * xv.y + wv.z * xv.z + wv.w * xv.w;
            }
        }
        acc = wave_sum(acc);
        if (lane == 0) gi[vec * 3072 + row] = acc + b_ih[row];
    }
}

// ---------------------------------------------------------------------------
// K3: dec[v] = out_W[v,1024:1252]·de + out_b[v]. 125 blocks x 256 (500 waves).
// ---------------------------------------------------------------------------
__global__ void k_dec(const float* __restrict__ oW,
                      const float* __restrict__ ob,
                      const float* __restrict__ de,
                      float* __restrict__ dec) {
    __shared__ float de_s[INSZ];
    const int t = threadIdx.x, w = t >> 6, lane = t & 63;
    for (int i = t; i < INSZ; i += 256) de_s[i] = de[i];
    __syncthreads();
    const int wg = blockIdx.x * 4 + w;  // 0..499, 64 rows each
    float4 xv = {0.f, 0.f, 0.f, 0.f};
    const int k = lane * 4;
    const bool act = k < INSZ;  // lanes 0..56
    if (act) xv = *(const float4*)(de_s + k);
    for (int rr = 0; rr < 64; rr++) {
        const int row = wg * 64 + rr;
        float acc = 0.f;
        if (act) {
            const float4 wv = *(const float4*)(oW + (size_t)row * XSZ + HID + k);
            acc = wv.x * xv.x + wv.y * xv.y + wv.z * xv.z + wv.w * xv.w;
        }
        acc = wave_sum(acc);
        if (lane == 0) dec[row] = acc + ob[row];
    }
}

// ---------------------------------------------------------------------------
// K4 (cooperative): 512-step GRU scan. 256 blocks x 256 threads.
// Block g, wave w owns hidden unit j = 4g+w; its 3 W_hh rows (fp32) in LDS.
// h ping-pongs in global fp32; one grid.sync per step. hs written as bf16.
// ---------------------------------------------------------------------------
__global__ void __launch_bounds__(256)
k_scan(const float* __restrict__ W_hh,
       const float* __restrict__ b_hh,
       const float* __restrict__ gi,        // [2][3072]
       float* __restrict__ hbuf,            // [2][1024], [0] = h0 from k_setup
       __hip_bfloat16* __restrict__ hs) {   // [512][1024]
    __shared__ float w_s[12 * HID];  // 48 KB: 4 waves x 3 rows x 1024 fp32
    const int t = threadIdx.x, w = t >> 6, lane = t & 63;
    const int j = blockIdx.x * 4 + w;
    // stage W_hh rows {j, 1024+j, 2048+j} (4KB-aligned rows) -> LDS
#pragma unroll
    for (int p = 0; p < 3; p++) {
        const float* wr = W_hh + (size_t)(p * HID + j) * HID;
        float* dst = w_s + (w * 3 + p) * HID;
        for (int k = lane * 4; k < HID; k += 256)
            *(float4*)(dst + k) = *(const float4*)(wr + k);
    }
    const float br = b_hh[j], bu = b_hh[HID + j], bn = b_hh[2 * HID + j];
    const float gsr = gi[j],        gsu = gi[HID + j],        gsn = gi[2 * HID + j];
    const float gur = gi[3072 + j], guu = gi[3072 + HID + j], gun = gi[3072 + 2 * HID + j];
    const float* wsr = w_s + (w * 3 + 0) * HID;
    const float* wsu = w_s + (w * 3 + 1) * HID;
    const float* wsn = w_s + (w * 3 + 2) * HID;
    __syncthreads();
    cg::grid_group grid = cg::this_grid();
    for (int step = 0; step < NSTEPS; step++) {
        const float* hc = hbuf + (step & 1) * HID;
        float pr = 0.f, pu = 0.f, pn = 0.f;
#pragma unroll
        for (int cc = 0; cc < 4; cc++) {
            const int k = cc * 256 + lane * 4;
            const float4 hv = *(const float4*)(hc + k);
            const float4 a = *(const float4*)(wsr + k);
            const float4 b = *(const float4*)(wsu + k);
            const float4 d = *(const float4*)(wsn + k);
            pr += hv.x * a.x + hv.y * a.y + hv.z * a.z + hv.w * a.w;
            pu += hv.x * b.x + hv.y * b.y + hv.z * b.z + hv.w * b.w;
            pn += hv.x * d.x + hv.y * d.y + hv.z * d.z + hv.w * d.w;
        }
        pr = wave_sum(pr); pu = wave_sum(pu); pn = wave_sum(pn);
        if (lane == 0) {
            const float ghr = pr + br, ghu = pu + bu, ghn = pn + bn;
            const float gir = step ? gur : gsr;
            const float giu = step ? guu : gsu;
            const float gin = step ? gun : gsn;
            const float rg = 1.f / (1.f + __expf(-(gir + ghr)));
            const float ug = 1.f / (1.f + __expf(-(giu + ghu)));
            const float ng = tanhf(gin + rg * ghn);
            const float hnew = (1.f - ug) * ng + ug * hc[j];
            hbuf[((step + 1) & 1) * HID + j] = hnew;
            hs[(size_t)step * HID + j] = __float2bfloat16(hnew);
        }
        grid.sync();
    }
}

// ---------------------------------------------------------------------------
// K5: out[512,32000] (fp32) = hs[512,1024](bf16) @ out_W[:, :1024]^T + dec.
// 128x128 tiles, BK=32, 4 waves x 4x4 mfma_f32_16x16x32_bf16.
// A via global_load_lds(16B) from bf16 hs; B read fp32 (2x float4, 16B
// aligned: row stride 5008B) and converted to bf16 during LDS staging.
// ---------------------------------------------------------------------------
__global__ void __launch_bounds__(256)
k_gemm(const __hip_bfloat16* __restrict__ hs,
       const float* __restrict__ oW,
       const float* __restrict__ dec,
       float* __restrict__ out) {
    __shared__ __hip_bfloat16 As[128 * 32];
    __shared__ __hip_bfloat16 Bs[128 * 32];
    const int t = threadIdx.x;
    const int m0 = blockIdx.x * 128;   // 4 M-tiles
    const int n0 = blockIdx.y * 128;   // 250 N-tiles
    const int w = t >> 6, lane = t & 63;
    const int wm = w & 1, wn = w >> 1;
    const int quad = lane >> 4, l16 = lane & 15;
    f32x4 acc[4][4];
#pragma unroll
    for (int i = 0; i < 4; i++)
#pragma unroll
        for (int jj = 0; jj < 4; jj++) acc[i][jj] = (f32x4){0.f, 0.f, 0.f, 0.f};

    const int r = t >> 2, c = t & 3;   // tile row 0..63, 8-elem chunk 0..3
    const __hip_bfloat16* aG0 = hs + (size_t)(m0 + r) * HID + c * 8;
    const __hip_bfloat16* aG1 = hs + (size_t)(m0 + r + 64) * HID + c * 8;
    const float* bG0 = oW + (size_t)(n0 + r) * XSZ + c * 8;
    const float* bG1 = oW + (size_t)(n0 + r + 64) * XSZ + c * 8;
    __hip_bfloat16* aL0 = As + t * 8;
    __hip_bfloat16* aL1 = As + (t + 256) * 8;
    __hip_bfloat16* bL0 = Bs + t * 8;
    __hip_bfloat16* bL1 = Bs + (t + 256) * 8;

    for (int k0 = 0; k0 < HID; k0 += 32) {
        __syncthreads();
        __builtin_amdgcn_global_load_lds(
            (const __attribute__((address_space(1))) void*)(aG0 + k0),
            (__attribute__((address_space(3))) void*)aL0, 16, 0, 0);
        __builtin_amdgcn_global_load_lds(
            (const __attribute__((address_space(1))) void*)(aG1 + k0),
            (__attribute__((address_space(3))) void*)aL1, 16, 0, 0);
        const float4 f00 = *(const float4*)(bG0 + k0);
        const float4 f01 = *(const float4*)(bG0 + k0 + 4);
        const float4 f10 = *(const float4*)(bG1 + k0);
        const float4 f11 = *(const float4*)(bG1 + k0 + 4);
        union { bf16x8 v; __hip_bfloat16 h[8]; } u0, u1;
        u0.h[0] = __float2bfloat16(f00.x); u0.h[1] = __float2bfloat16(f00.y);
        u0.h[2] = __float2bfloat16(f00.z); u0.h[3] = __float2bfloat16(f00.w);
        u0.h[4] = __float2bfloat16(f01.x); u0.h[5] = __float2bfloat16(f01.y);
        u0.h[6] = __float2bfloat16(f01.z); u0.h[7] = __float2bfloat16(f01.w);
        u1.h[0] = __float2bfloat16(f10.x); u1.h[1] = __float2bfloat16(f10.y);
        u1.h[2] = __float2bfloat16(f10.z); u1.h[3] = __float2bfloat16(f10.w);
        u1.h[4] = __float2bfloat16(f11.x); u1.h[5] = __float2bfloat16(f11.y);
        u1.h[6] = __float2bfloat16(f11.z); u1.h[7] = __float2bfloat16(f11.w);
        *(bf16x8*)bL0 = u0.v;
        *(bf16x8*)bL1 = u1.v;
        __syncthreads();
        bf16x8 af[4], bfv[4];
#pragma unroll
        for (int mi = 0; mi < 4; mi++)
            af[mi] = *(const bf16x8*)(As + (wm * 64 + mi * 16 + l16) * 32 + quad * 8);
#pragma unroll
        for (int ni = 0; ni < 4; ni++)
            bfv[ni] = *(const bf16x8*)(Bs + (wn * 64 + ni * 16 + l16) * 32 + quad * 8);
#pragma unroll
        for (int mi = 0; mi < 4; mi++)
#pragma unroll
            for (int ni = 0; ni < 4; ni++)
                acc[mi][ni] = __builtin_amdgcn_mfma_f32_16x16x32_bf16(
                    af[mi], bfv[ni], acc[mi][ni], 0, 0, 0);
    }
    float dc[4];
#pragma unroll
    for (int ni = 0; ni < 4; ni++) dc[ni] = dec[n0 + wn * 64 + ni * 16 + l16];
#pragma unroll
    for (int mi = 0; mi < 4; mi++)
#pragma unroll
        for (int ni = 0; ni < 4; ni++) {
            const int col = n0 + wn * 64 + ni * 16 + l16;
#pragma unroll
            for (int rr = 0; rr < 4; rr++) {
                const int row = m0 + wm * 64 + mi * 16 + quad * 4 + rr;
                out[(size_t)row * NVOCAB + col] = acc[mi][ni][rr] + dc[ni];
            }
        }
}

// ---------------------------------------------------------------------------
extern "C" void kernel_launch(void* const* d_in, const int* in_sizes, int n_in,
                              void* d_out, int out_size, void* d_ws, size_t ws_size,
                              hipStream_t stream) {
    const float* z      = (const float*)d_in[0];
    const float* cond   = (const float*)d_in[1];
    // d_in[2] = inputs (int32, unused: word_dropout=1.0), d_in[3] = temperature (unused)
    const float* embedW = (const float*)d_in[4];
    const float* W_ih   = (const float*)d_in[5];
    const float* W_hh   = (const float*)d_in[6];
    const float* b_ih   = (const float*)d_in[7];
    const float* b_hh   = (const float*)d_in[8];
    const float* i2hW   = (const float*)d_in[9];
    const float* i2hb   = (const float*)d_in[10];
    const float* c2hW   = (const float*)d_in[11];
    const float* c2hb   = (const float*)d_in[12];
    const float* outW   = (const float*)d_in[13];
    const float* outb   = (const float*)d_in[14];
    float* out = (float*)d_out;

    // workspace (fp32 words): de[0,256) gi[256,6400) hbuf[6400,8448)
    // dec[8448,40448) ; hs (bf16) at byte 161792 (16B aligned), 1 MB.
    float* ws   = (float*)d_ws;
    float* de   = ws + 0;
    float* gi   = ws + 256;
    float* hbuf = ws + 6400;
    float* dec  = ws + 8448;
    __hip_bfloat16* hs = (__hip_bfloat16*)((char*)d_ws + 40448 * 4);

    k_setup<<<4, 256, 0, stream>>>(z, cond, i2hW, i2hb, c2hW, c2hb, de, hbuf);
    k_gi<<<96, 256, 0, stream>>>(embedW, W_ih, b_ih, de, gi);
    k_dec<<<125, 256, 0, stream>>>(outW, outb, de, dec);

    void* args[] = { (void*)&W_hh, (void*)&b_hh, (void*)&gi, (void*)&hbuf, (void*)&hs };
    hipLaunchCooperativeKernel((void*)k_scan, dim3(256), dim3(256), args, 0, stream);

    k_gemm<<<dim3(4, 250), 256, 0, stream>>>(hs, outW, dec, out);
}

// Round 3
// 3307.224 us; speedup vs baseline: 4.6555x; 4.6555x over previous
//
#include <hip/hip_runtime.h>
#include <hip/hip_bf16.h>

// Problem constants
#define HID    1024
#define ZS     128
#define NCOND  40
#define CSIZE  100
#define INSZ   228      // ZS + CSIZE
#define XSZ    1252     // HID + INSZ
#define NVOCAB 32000
#define NSTEPS 512
#define NBLK   64       // k_scan blocks; 64 flags == 64 lanes of the poll wave

typedef __attribute__((ext_vector_type(8))) short bf16x8;
typedef __attribute__((ext_vector_type(4))) float f32x4;

__device__ __forceinline__ float wave_sum(float v) {
#pragma unroll
    for (int off = 32; off > 0; off >>= 1) v += __shfl_xor(v, off);
    return v;
}

// ---------------------------------------------------------------------------
// K1: de = [z, c2h(cond)] (fp32), h0 = i2h(de) -> hbuf[0:1024]; init flags.
// grid 4 x 256.
// ---------------------------------------------------------------------------
__global__ void k_setup(const float* __restrict__ z,
                        const float* __restrict__ cond,
                        const float* __restrict__ i2hW,
                        const float* __restrict__ i2hb,
                        const float* __restrict__ c2hW,
                        const float* __restrict__ c2hb,
                        float* __restrict__ de, float* __restrict__ h0,
                        int* __restrict__ flags) {
    __shared__ float de_s[INSZ];
    const int t = threadIdx.x;
    if (blockIdx.x == 0 && t < NBLK) flags[t] = 0;
    if (t < ZS) {
        de_s[t] = z[t];
    } else if (t < INSZ) {
        const int i = t - ZS;
        float acc = c2hb[i];
        for (int k = 0; k < NCOND; k++)
            acc += c2hW[i * NCOND + k] * cond[k];
        de_s[t] = acc;
    }
    __syncthreads();
    if (blockIdx.x == 0 && t < INSZ) de[t] = de_s[t];
    const int r = blockIdx.x * 256 + t;   // 0..1023
    float acc = i2hb[r];
    const float* w = i2hW + (size_t)r * INSZ;   // 912B row stride, 16B aligned
#pragma unroll 8
    for (int k = 0; k < INSZ; k += 4) {
        const float4 wv = *(const float4*)(w + k);
        const float4 xv = *(const float4*)(de_s + k);
        acc += wv.x * xv.x + wv.y * xv.y + wv.z * xv.z + wv.w * xv.w;
    }
    h0[r] = acc;
}

// ---------------------------------------------------------------------------
// K2: gi[vec][3072] = W_ih @ [relu(embed[tok]), de] + b_ih, vec 0=SOS 1=UNK.
// grid 96 x 256: vec = bid&1, rows (bid>>1)*64 .. +64.
// ---------------------------------------------------------------------------
__global__ void k_gi(const float* __restrict__ embedW,
                     const float* __restrict__ W_ih,
                     const float* __restrict__ b_ih,
                     const float* __restrict__ de,
                     float* __restrict__ gi) {
    __shared__ float x_s[XSZ];
    const int g = blockIdx.x, t = threadIdx.x;
    const int vec = g & 1, rb = g >> 1;
    const int tok = 1 + vec;  // SOS=1, UNK=2
    for (int i = t; i < HID; i += 256) {
        float e = embedW[(size_t)tok * HID + i];
        x_s[i] = e > 0.f ? e : 0.f;
    }
    for (int i = t; i < INSZ; i += 256) x_s[HID + i] = de[i];
    __syncthreads();
    const int w = t >> 6, lane = t & 63;
    for (int rr = 0; rr < 16; rr++) {
        const int row = rb * 64 + w * 16 + rr;
        const float* wr = W_ih + (size_t)row * XSZ;  // 5008B stride, 16B aligned
        float acc = 0.f;
#pragma unroll
        for (int cc = 0; cc < 5; cc++) {
            const int k = cc * 256 + lane * 4;
            if (k < XSZ) {
                const float4 wv = *(const float4*)(wr + k);
                const float4 xv = *(const float4*)(x_s + k);
                acc += wv.x * xv.x + wv.y * xv.y + wv.z * xv.z + wv.w * xv.w;
            }
        }
        acc = wave_sum(acc);
        if (lane == 0) gi[vec * 3072 + row] = acc + b_ih[row];
    }
}

// ---------------------------------------------------------------------------
// K3: dec[v] = out_W[v,1024:1252]·de + out_b[v]. 125 blocks x 256 (500 waves).
// ---------------------------------------------------------------------------
__global__ void k_dec(const float* __restrict__ oW,
                      const float* __restrict__ ob,
                      const float* __restrict__ de,
                      float* __restrict__ dec) {
    __shared__ float de_s[INSZ];
    const int t = threadIdx.x, w = t >> 6, lane = t & 63;
    for (int i = t; i < INSZ; i += 256) de_s[i] = de[i];
    __syncthreads();
    const int wg = blockIdx.x * 4 + w;  // 0..499, 64 rows each
    float4 xv = {0.f, 0.f, 0.f, 0.f};
    const int k = lane * 4;
    const bool act = k < INSZ;  // lanes 0..56
    if (act) xv = *(const float4*)(de_s + k);
    for (int rr = 0; rr < 64; rr++) {
        const int row = wg * 64 + rr;
        float acc = 0.f;
        if (act) {
            const float4 wv = *(const float4*)(oW + (size_t)row * XSZ + HID + k);
            acc = wv.x * xv.x + wv.y * xv.y + wv.z * xv.z + wv.w * xv.w;
        }
        acc = wave_sum(acc);
        if (lane == 0) dec[row] = acc + ob[row];
    }
}

// ---------------------------------------------------------------------------
// K4 (cooperative): 512-step GRU scan, custom single-hop flag barrier.
// 64 blocks x 1024 threads. Wave w of block b owns hidden unit j = 16b + w;
// its 3 fp32 W_hh rows live in VGPRs (lane l holds k in [16l,16l+16)).
// h ping-pongs in global fp32 via agent-scope stores; hs written as bf16.
// Barrier: flags[b]=step+1 (release), wave 0 polls all 64 flags (one per
// lane), agent-acquire fence, __syncthreads. No atomic RMW, no sleep loop.
// ---------------------------------------------------------------------------
__global__ void __launch_bounds__(1024, 4)
k_scan(const float* __restrict__ W_hh,
       const float* __restrict__ b_hh,
       const float* __restrict__ gi,        // [2][3072]
       float* __restrict__ hbuf,            // [2][1024], [0] = h0 from k_setup
       __hip_bfloat16* __restrict__ hs,     // [512][1024]
       int* __restrict__ flags) {           // [NBLK]
    const int t = threadIdx.x, w = t >> 6, lane = t & 63;
    const int j = blockIdx.x * 16 + w;      // hidden unit owned by this wave
    const int k0 = lane * 16;               // this lane's k-range start

    // W_hh rows {j, 1024+j, 2048+j} -> registers (12 x float4, coalesced)
    float4 wreg[3][4];
#pragma unroll
    for (int p = 0; p < 3; p++) {
        const float* wr = W_hh + (size_t)(p * HID + j) * HID + k0;
#pragma unroll
        for (int c = 0; c < 4; c++) wreg[p][c] = *(const float4*)(wr + c * 4);
    }
    const float br = b_hh[j], bu = b_hh[HID + j], bn = b_hh[2 * HID + j];
    const float gsr = gi[j],        gsu = gi[HID + j],        gsn = gi[2 * HID + j];
    const float gur = gi[3072 + j], guu = gi[3072 + HID + j], gun = gi[3072 + 2 * HID + j];

    for (int step = 0; step < NSTEPS; step++) {
        const float* hc = hbuf + (step & 1) * HID;
        // lane 0 also needs old h[j] for the update-gate blend; issue early
        float hold = 0.f;
        if (lane == 0) hold = hc[j];
        float4 hv[4];
#pragma unroll
        for (int c = 0; c < 4; c++) hv[c] = *(const float4*)(hc + k0 + c * 4);
        float pr = 0.f, pu = 0.f, pn = 0.f;
#pragma unroll
        for (int c = 0; c < 4; c++) {
            pr += wreg[0][c].x * hv[c].x + wreg[0][c].y * hv[c].y
                + wreg[0][c].z * hv[c].z + wreg[0][c].w * hv[c].w;
            pu += wreg[1][c].x * hv[c].x + wreg[1][c].y * hv[c].y
                + wreg[1][c].z * hv[c].z + wreg[1][c].w * hv[c].w;
            pn += wreg[2][c].x * hv[c].x + wreg[2][c].y * hv[c].y
                + wreg[2][c].z * hv[c].z + wreg[2][c].w * hv[c].w;
        }
        pr = wave_sum(pr); pu = wave_sum(pu); pn = wave_sum(pn);
        if (lane == 0) {
            const float ghr = pr + br, ghu = pu + bu, ghn = pn + bn;
            const float gir = step ? gur : gsr;
            const float giu = step ? guu : gsu;
            const float gin = step ? gun : gsn;
            const float rg = 1.f / (1.f + __expf(-(gir + ghr)));
            const float ug = 1.f / (1.f + __expf(-(giu + ghu)));
            const float ng = tanhf(gin + rg * ghn);
            const float hnew = (1.f - ug) * ng + ug * hold;
            // write-through to LLC so all XCDs see it after the flag
            __hip_atomic_store(hbuf + (((step + 1) & 1) * HID + j), hnew,
                               __ATOMIC_RELAXED, __HIP_MEMORY_SCOPE_AGENT);
            hs[(size_t)step * HID + j] = __float2bfloat16(hnew);
        }
        if (step == NSTEPS - 1) break;   // kernel boundary covers hs -> k_gemm
        // ---- single-hop grid barrier ----
        __syncthreads();                 // drains each wave's stores (vmcnt)
        if (t == 0)
            __hip_atomic_store(flags + blockIdx.x, step + 1,
                               __ATOMIC_RELEASE, __HIP_MEMORY_SCOPE_AGENT);
        if (w == 0) {
            int v;
            do {
                v = __hip_atomic_load(flags + lane, __ATOMIC_RELAXED,
                                      __HIP_MEMORY_SCOPE_AGENT);
            } while (__any(v < step + 1));
            __builtin_amdgcn_fence(__ATOMIC_ACQUIRE, "agent");
        }
        __syncthreads();
    }
}

// ---------------------------------------------------------------------------
// K5: out[512,32000] (fp32) = hs[512,1024](bf16) @ out_W[:, :1024]^T + dec.
// 128x128 tiles, BK=32, 4 waves x 4x4 mfma_f32_16x16x32_bf16.
// ---------------------------------------------------------------------------
__global__ void __launch_bounds__(256)
k_gemm(const __hip_bfloat16* __restrict__ hs,
       const float* __restrict__ oW,
       const float* __restrict__ dec,
       float* __restrict__ out) {
    __shared__ __hip_bfloat16 As[128 * 32];
    __shared__ __hip_bfloat16 Bs[128 * 32];
    const int t = threadIdx.x;
    const int m0 = blockIdx.x * 128;   // 4 M-tiles
    const int n0 = blockIdx.y * 128;   // 250 N-tiles
    const int w = t >> 6, lane = t & 63;
    const int wm = w & 1, wn = w >> 1;
    const int quad = lane >> 4, l16 = lane & 15;
    f32x4 acc[4][4];
#pragma unroll
    for (int i = 0; i < 4; i++)
#pragma unroll
        for (int jj = 0; jj < 4; jj++) acc[i][jj] = (f32x4){0.f, 0.f, 0.f, 0.f};

    const int r = t >> 2, c = t & 3;   // tile row 0..63, 8-elem chunk 0..3
    const __hip_bfloat16* aG0 = hs + (size_t)(m0 + r) * HID + c * 8;
    const __hip_bfloat16* aG1 = hs + (size_t)(m0 + r + 64) * HID + c * 8;
    const float* bG0 = oW + (size_t)(n0 + r) * XSZ + c * 8;
    const float* bG1 = oW + (size_t)(n0 + r + 64) * XSZ + c * 8;
    __hip_bfloat16* aL0 = As + t * 8;
    __hip_bfloat16* aL1 = As + (t + 256) * 8;
    __hip_bfloat16* bL0 = Bs + t * 8;
    __hip_bfloat16* bL1 = Bs + (t + 256) * 8;

    for (int k0 = 0; k0 < HID; k0 += 32) {
        __syncthreads();
        __builtin_amdgcn_global_load_lds(
            (const __attribute__((address_space(1))) void*)(aG0 + k0),
            (__attribute__((address_space(3))) void*)aL0, 16, 0, 0);
        __builtin_amdgcn_global_load_lds(
            (const __attribute__((address_space(1))) void*)(aG1 + k0),
            (__attribute__((address_space(3))) void*)aL1, 16, 0, 0);
        const float4 f00 = *(const float4*)(bG0 + k0);
        const float4 f01 = *(const float4*)(bG0 + k0 + 4);
        const float4 f10 = *(const float4*)(bG1 + k0);
        const float4 f11 = *(const float4*)(bG1 + k0 + 4);
        union { bf16x8 v; __hip_bfloat16 h[8]; } u0, u1;
        u0.h[0] = __float2bfloat16(f00.x); u0.h[1] = __float2bfloat16(f00.y);
        u0.h[2] = __float2bfloat16(f00.z); u0.h[3] = __float2bfloat16(f00.w);
        u0.h[4] = __float2bfloat16(f01.x); u0.h[5] = __float2bfloat16(f01.y);
        u0.h[6] = __float2bfloat16(f01.z); u0.h[7] = __float2bfloat16(f01.w);
        u1.h[0] = __float2bfloat16(f10.x); u1.h[1] = __float2bfloat16(f10.y);
        u1.h[2] = __float2bfloat16(f10.z); u1.h[3] = __float2bfloat16(f10.w);
        u1.h[4] = __float2bfloat16(f11.x); u1.h[5] = __float2bfloat16(f11.y);
        u1.h[6] = __float2bfloat16(f11.z); u1.h[7] = __float2bfloat16(f11.w);
        *(bf16x8*)bL0 = u0.v;
        *(bf16x8*)bL1 = u1.v;
        __syncthreads();
        bf16x8 af[4], bfv[4];
#pragma unroll
        for (int mi = 0; mi < 4; mi++)
            af[mi] = *(const bf16x8*)(As + (wm * 64 + mi * 16 + l16) * 32 + quad * 8);
#pragma unroll
        for (int ni = 0; ni < 4; ni++)
            bfv[ni] = *(const bf16x8*)(Bs + (wn * 64 + ni * 16 + l16) * 32 + quad * 8);
#pragma unroll
        for (int mi = 0; mi < 4; mi++)
#pragma unroll
            for (int ni = 0; ni < 4; ni++)
                acc[mi][ni] = __builtin_amdgcn_mfma_f32_16x16x32_bf16(
                    af[mi], bfv[ni], acc[mi][ni], 0, 0, 0);
    }
    float dc[4];
#pragma unroll
    for (int ni = 0; ni < 4; ni++) dc[ni] = dec[n0 + wn * 64 + ni * 16 + l16];
#pragma unroll
    for (int mi = 0; mi < 4; mi++)
#pragma unroll
        for (int ni = 0; ni < 4; ni++) {
            const int col = n0 + wn * 64 + ni * 16 + l16;
#pragma unroll
            for (int rr = 0; rr < 4; rr++) {
                const int row = m0 + wm * 64 + mi * 16 + quad * 4 + rr;
                out[(size_t)row * NVOCAB + col] = acc[mi][ni][rr] + dc[ni];
            }
        }
}

// ---------------------------------------------------------------------------
extern "C" void kernel_launch(void* const* d_in, const int* in_sizes, int n_in,
                              void* d_out, int out_size, void* d_ws, size_t ws_size,
                              hipStream_t stream) {
    const float* z      = (const float*)d_in[0];
    const float* cond   = (const float*)d_in[1];
    // d_in[2] = inputs (int32, unused: word_dropout=1.0), d_in[3] = temperature (unused)
    const float* embedW = (const float*)d_in[4];
    const float* W_ih   = (const float*)d_in[5];
    const float* W_hh   = (const float*)d_in[6];
    const float* b_ih   = (const float*)d_in[7];
    const float* b_hh   = (const float*)d_in[8];
    const float* i2hW   = (const float*)d_in[9];
    const float* i2hb   = (const float*)d_in[10];
    const float* c2hW   = (const float*)d_in[11];
    const float* c2hb   = (const float*)d_in[12];
    const float* outW   = (const float*)d_in[13];
    const float* outb   = (const float*)d_in[14];
    float* out = (float*)d_out;

    // workspace (fp32 words): de[0,256) gi[256,6400) hbuf[6400,8448)
    // dec[8448,40448) flags[40448,40512) ; hs (bf16) at word 40576, 1 MB.
    float* ws   = (float*)d_ws;
    float* de   = ws + 0;
    float* gi   = ws + 256;
    float* hbuf = ws + 6400;
    float* dec  = ws + 8448;
    int*   flags = (int*)(ws + 40448);
    __hip_bfloat16* hs = (__hip_bfloat16*)(ws + 40576);

    k_setup<<<4, 256, 0, stream>>>(z, cond, i2hW, i2hb, c2hW, c2hb, de, hbuf, flags);
    k_gi<<<96, 256, 0, stream>>>(embedW, W_ih, b_ih, de, gi);
    k_dec<<<125, 256, 0, stream>>>(outW, outb, de, dec);

    void* args[] = { (void*)&W_hh, (void*)&b_hh, (void*)&gi, (void*)&hbuf,
                     (void*)&hs, (void*)&flags };
    hipLaunchCooperativeKernel((void*)k_scan, dim3(NBLK), dim3(1024), args, 0, stream);

    k_gemm<<<dim3(4, 250), 256, 0, stream>>>(hs, outW, dec, out);
}